// Round 9
// baseline (162.494 us; speedup 1.0000x reference)
//
#include <hip/hip_runtime.h>

// DualMem fast_get_image_pred:
//   logits[b,c] = 100 * (Σ_m w_m sim_m) / sqrt(Σ_{i,j} w_i w_j G[c,i,j])
//
// Lesson ledger (9 rounds):
//  - Spill signature = all-pipes-idle + scratch writes. Triggers observed:
//    R1(launch_bounds 2nd arg=4 -> VGPR 64), R5(320-thr -> 88),
//    R7((256,2) -> 88), R8(plain(256) but 52KB LDS -> 84).
//    Revised rule: blocks with >=48KB LDS get starved VGPR allocations on
//    this compiler regardless of launch_bounds; LDS-free kernels get
//    136-144. => avoid big-LDS fused designs entirely.
//  - R4: loads whose address ignores lane bits are wave-duplicated through
//    L1 (16x dup = 3.1GB = 105us). => lane-distinct addresses (d = 4*l).
//  - R6: (a) sched_barrier(0) fences pin compile order and serialize load
//    latency — never fence; use #pragma unroll 1 to bound transients.
//    (b) grid (4,1000) puts same-class siblings on 4 XCDs (4x L2 fill dup).
//    grid (1000,4) + 1000%8==0 puts them all on XCD c%8.
//
// Structure: 3 simple kernels, zero LDS in hot paths, no fences.
//   K1 sim:  grid(1000,4); wave owns 4 b-rows; lane l owns d=4l+256k.
//   K2 gram: grid(1000); R4-proven 17-pair compile-time groups.
//   K3 finish: grid(250); trivial.

constexpr int Bn = 64;     // batch
constexpr int Cn = 1000;   // classes
constexpr int Mn = 11;     // memories per class
constexpr int Dn = 1024;   // feature dim
constexpr int NP = 66;     // Mn*(Mn+1)/2 unique Gram pairs
constexpr float BETA = 5.5f;

// p-th pair (i<=j) of the upper-triangular 11x11 Gram (compile-time p only!)
constexpr int pairI(int p) {
    int i = 0;
    while (p >= Mn - i) { p -= Mn - i; ++i; }
    return i;
}
constexpr int pairJ(int p) {
    int i = 0;
    while (p >= Mn - i) { p -= Mn - i; ++i; }
    return i + p;
}

// ---------------- K1: sim[c][b][m] ----------------
__global__ __launch_bounds__(256) void sim_kernel(
    const float* __restrict__ img, const float* __restrict__ mem,
    float* __restrict__ sim) {
    const int c  = blockIdx.x;         // class; XCD = c%8 (1000%8==0 keeps
    const int jq = blockIdx.y;         // all 4 siblings of c on one XCD)
    const int w  = threadIdx.x >> 6;   // wave 0..3
    const int l  = threadIdx.x & 63;   // lane: d = 4*l + 256*k + {0..3}
    const int b0 = jq * 16 + w * 4;    // this wave's 4 b-rows

    const float* ip = img + b0 * Dn + 4 * l;
    const float* mp = mem + (size_t)c * (Mn * Dn) + 4 * l;

    float acc[4][Mn];
#pragma unroll
    for (int i = 0; i < 4; ++i)
#pragma unroll
        for (int m = 0; m < Mn; ++m) acc[i][m] = 0.f;

#pragma unroll 1
    for (int k = 0; k < 4; ++k) {      // unroll 1: bound transient pressure
        float4 iv[4];
#pragma unroll
        for (int i = 0; i < 4; ++i)
            iv[i] = *reinterpret_cast<const float4*>(ip + i * Dn + 256 * k);
#pragma unroll
        for (int m = 0; m < Mn; ++m) {
            const float4 mv = *reinterpret_cast<const float4*>(mp + m * Dn + 256 * k);
#pragma unroll
            for (int i = 0; i < 4; ++i) {
                float a = acc[i][m];
                a = fmaf(iv[i].x, mv.x, a);
                a = fmaf(iv[i].y, mv.y, a);
                a = fmaf(iv[i].z, mv.z, a);
                a = fmaf(iv[i].w, mv.w, a);
                acc[i][m] = a;
            }
        }
    }

    // full 64-lane butterfly reduce of each of the 44 partial dots
#pragma unroll
    for (int i = 0; i < 4; ++i)
#pragma unroll
        for (int m = 0; m < Mn; ++m) {
            float x = acc[i][m];
            x += __shfl_xor(x, 1, 64);
            x += __shfl_xor(x, 2, 64);
            x += __shfl_xor(x, 4, 64);
            x += __shfl_xor(x, 8, 64);
            x += __shfl_xor(x, 16, 64);
            x += __shfl_xor(x, 32, 64);
            acc[i][m] = x;
        }

    if (l == 0) {
        float* o = sim + (size_t)c * (Bn * Mn) + b0 * Mn;  // 44 contiguous floats
#pragma unroll
        for (int i = 0; i < 4; ++i)
#pragma unroll
            for (int m = 0; m < Mn; ++m) o[i * Mn + m] = acc[i][m];
    }
}

// ---------------- K2: gram[c][p] ----------------
template <int P0, int P1>
__device__ inline void gramPairs(const float4* v, float* g) {
#pragma unroll
    for (int p = P0; p < P1; ++p) {           // p compile-time after unroll
        const float4 a = v[pairI(p)];
        const float4 b = v[pairJ(p)];
        float x = g[p - P0];
        x = fmaf(a.x, b.x, x);
        x = fmaf(a.y, b.y, x);
        x = fmaf(a.z, b.z, x);
        x = fmaf(a.w, b.w, x);
        g[p - P0] = x;
    }
}

__global__ __launch_bounds__(256) void gram_kernel(
    const float* __restrict__ mem, float* __restrict__ gram) {
    const int c = blockIdx.x;
    const int w = threadIdx.x >> 6;    // wave: pair group
    const int l = threadIdx.x & 63;    // lane: d = 4*l + 256*k + {0..3}

    const float* mp = mem + (size_t)c * (Mn * Dn) + 4 * l;

    float g[17];
#pragma unroll
    for (int q = 0; q < 17; ++q) g[q] = 0.f;

#pragma unroll 1
    for (int k = 0; k < 4; ++k) {
        float4 v[Mn];
#pragma unroll
        for (int m = 0; m < Mn; ++m)
            v[m] = *reinterpret_cast<const float4*>(mp + m * Dn + 256 * k);
        if (w == 0)      gramPairs<0, 17>(v, g);
        else if (w == 1) gramPairs<17, 34>(v, g);
        else if (w == 2) gramPairs<34, 50>(v, g);
        else             gramPairs<50, 66>(v, g);
    }
#pragma unroll
    for (int q = 0; q < 17; ++q) {
        float x = g[q];
        x += __shfl_xor(x, 1, 64);
        x += __shfl_xor(x, 2, 64);
        x += __shfl_xor(x, 4, 64);
        x += __shfl_xor(x, 8, 64);
        x += __shfl_xor(x, 16, 64);
        x += __shfl_xor(x, 32, 64);
        g[q] = x;
    }
    const int np = (w < 2) ? 17 : 16;
    const int p0 = (w == 0) ? 0 : (w == 1) ? 17 : (w == 2) ? 34 : 50;
    if (l == 0) {
#pragma unroll
        for (int q = 0; q < 17; ++q)          // q compile-time, guard runtime
            if (q < np) gram[c * NP + p0 + q] = g[q];
    }
}

// ---------------- K3: logits ----------------
__global__ __launch_bounds__(256) void finish_kernel(
    const float* __restrict__ sim, const float* __restrict__ gram,
    float* __restrict__ out) {
    const int b = threadIdx.x & 63;
    const int c = blockIdx.x * 4 + (threadIdx.x >> 6);

    const float* sp = sim + (size_t)c * (Bn * Mn) + b * Mn;
    const float* gp = gram + c * NP;

    float w[Mn];
    float numer = 0.f;
#pragma unroll
    for (int m = 0; m < Mn; ++m) {
        const float s = sp[m];
        w[m]  = __expf(BETA * (s - 1.f));
        numer = fmaf(w[m], s, numer);
    }
    float den2 = 0.f;
#pragma unroll
    for (int p = 0; p < NP; ++p) {
        const float t = w[pairI(p)] * w[pairJ(p)] * gp[p];
        den2 += (pairI(p) == pairJ(p)) ? t : (2.f * t);
    }
    out[b * Cn + c] = 100.f * numer / sqrtf(den2);
}

extern "C" void kernel_launch(void* const* d_in, const int* in_sizes, int n_in,
                              void* d_out, int out_size, void* d_ws, size_t ws_size,
                              hipStream_t stream) {
    const float* img = (const float*)d_in[0];  // [64][1024] f32
    const float* mem = (const float*)d_in[1];  // [1000][11][1024] f32
    float* out = (float*)d_out;                // [64][1000] f32
    (void)in_sizes; (void)n_in; (void)out_size; (void)ws_size;

    float* ws_sim  = (float*)d_ws;             // [1000][64][11]
    float* ws_gram = ws_sim + Cn * Bn * Mn;    // [1000][66]

    sim_kernel<<<dim3(Cn, 4), dim3(256), 0, stream>>>(img, mem, ws_sim);
    gram_kernel<<<dim3(Cn), dim3(256), 0, stream>>>(mem, ws_gram);
    finish_kernel<<<dim3(Cn / 4), dim3(256), 0, stream>>>(ws_sim, ws_gram, out);
}